// Round 14
// baseline (2924.549 us; speedup 1.0000x reference)
//
#include <hip/hip_runtime.h>
#include <hip/hip_bf16.h>

#define N1 8192
#define N2 8192
#define CDIM 128
#define HC 60
#define WC 80
#define HIMG 480
#define WIMG 640
#define NPIX (HC * WC)
#define INV_DENOM (1.0f / (8192.0f * 256.0f))
#define T0KEY  0xC100u      // monotone key of bf16(8.0)
#define THIKEY 0xC200u      // monotone key of bf16(32.0)
#define ROWS_PB 16          // rows per block
#define RCAP 1536           // per-row candidate cap (mean ~1190, sigma ~35)

using bf16x8 = __attribute__((ext_vector_type(8))) short;
using f32x4  = __attribute__((ext_vector_type(4))) float;

__device__ __forceinline__ ushort f2bf(float f) {
    union { float f; unsigned u; } x; x.f = f;
    unsigned u = x.u;
    unsigned r = (u + 0x7FFFu + ((u >> 16) & 1u)) >> 16;
    return (ushort)r;
}
__device__ __forceinline__ float bf2f(unsigned bits) {
    union { unsigned u; float f; } x; x.u = bits << 16; return x.f;
}
__device__ __forceinline__ unsigned bits2key(unsigned b) {
    return b ^ ((b & 0x8000u) ? 0xFFFFu : 0x8000u);
}
__device__ __forceinline__ unsigned key2bits(unsigned k) {
    return k ^ ((k & 0x8000u) ? 0x8000u : 0xFFFFu);
}

// ---------- fp32 -> bf16 convert ----------
__global__ void cvt_kernel(const float* __restrict__ in, ushort* __restrict__ out, int n4) {
    int i = blockIdx.x * blockDim.x + threadIdx.x;
    if (i < n4) {
        float4 v = ((const float4*)in)[i];
        ushort4 o;
        o.x = f2bf(v.x); o.y = f2bf(v.y); o.z = f2bf(v.z); o.w = f2bf(v.w);
        ((ushort4*)out)[i] = o;
    }
}

// ---------- desc2 transpose, read-coalesced ----------
__global__ void tr_kernel(const float* __restrict__ in, float* __restrict__ out) {
    int e = blockIdx.x * blockDim.x + threadIdx.x;   // 614400 elements
    if (e < NPIX * CDIM) {
        int c = e / NPIX;
        int p = e - c * NPIX;
        out[(size_t)p * CDIM + c] = in[e];
    }
}

// ---------- positive term (coalesced, plain store) ----------
__global__ void pos_kernel(const float* __restrict__ wkp1,
                           const float* __restrict__ kp1d,
                           const float* __restrict__ desc2T,
                           float* __restrict__ ploss) {
    const int i = blockIdx.x;
    const int c = threadIdx.x;            // 128 threads = 2 waves
    float y = wkp1[2 * i], x = wkp1[2 * i + 1];
    float py = fminf(fmaxf(y / (float)(HIMG - 1) * (float)(HC - 1), 0.0f), (float)(HC - 1));
    float px = fminf(fmaxf(x / (float)(WIMG - 1) * (float)(WC - 1), 0.0f), (float)(WC - 1));
    int y0 = min(max((int)floorf(py), 0), HC - 2);
    int x0 = min(max((int)floorf(px), 0), WC - 2);
    float wy = py - (float)y0;
    float wx = px - (float)x0;
    const int p00 = y0 * WC + x0;
    float v00 = desc2T[(size_t)p00 * CDIM + c];
    float v01 = desc2T[(size_t)(p00 + 1) * CDIM + c];
    float v10 = desc2T[(size_t)(p00 + WC) * CDIM + c];
    float v11 = desc2T[(size_t)(p00 + WC + 1) * CDIM + c];
    float v = v00 * (1.0f - wy) * (1.0f - wx) + v01 * (1.0f - wy) * wx
            + v10 * wy * (1.0f - wx) + v11 * wy * wx;
    float a = kp1d[(size_t)i * CDIM + c];
    float s2 = v * v, sav = a * v;
    #pragma unroll
    for (int off = 32; off >= 1; off >>= 1) {
        s2  += __shfl_down(s2, off);
        sav += __shfl_down(sav, off);
    }
    __shared__ float p2[2], pav[2];
    int wave = threadIdx.x >> 6, lane = threadIdx.x & 63;
    if (lane == 0) { p2[wave] = s2; pav[wave] = sav; }
    __syncthreads();
    if (threadIdx.x == 0) {
        float nrm = sqrtf(p2[0] + p2[1]);
        float pd = (pav[0] + pav[1]) / fmaxf(nrm, 1e-12f);
        float l = fmaxf(1.0f - pd, 0.0f) * (256.0f / 3.0f);
        ploss[i] = l * INV_DENOM;
    }
}

// ---------- FUSED masked-GEMM + top-256 hinge select ----------
// dots NEVER touch HBM. Block = 16 rows x all 8192 cols; wave = 2048-col
// strip. A-frags hoisted to VGPRs; B global reads are L2-resident (2 MB
// fits per-XCD L2). Candidates (key > T0 = 8.0) go to per-row LDS lists via
// quad ballot + LDS atomic (distinct addrs). One barrier, then each wave
// bisects 4 rows' ~1190-entry lists (checked brackets; exact-recompute
// fallback to global scratch, never taken in practice).
__global__ __launch_bounds__(256)
void fused_kernel(const ushort* __restrict__ A, const ushort* __restrict__ B,
                  const float* __restrict__ wkp1, const float* __restrict__ kp2,
                  float* __restrict__ rloss, ushort* __restrict__ fb) {
    const int m0 = blockIdx.x * ROWS_PB;          // 512 blocks
    const int wave = threadIdx.x >> 6;
    const int lane = threadIdx.x & 63;
    const int lrow = lane & 15, quad = lane >> 4;
    const int colbase = wave * (N2 / 4);

    __shared__ ushort lists[ROWS_PB][RCAP];       // 48 KB
    __shared__ unsigned cnt[ROWS_PB];

    if (threadIdx.x < ROWS_PB) cnt[threadIdx.x] = 0u;
    __syncthreads();

    // hoist A-frags (rows m0..m0+15, lane row = lrow): 4 k-steps
    bf16x8 af[4];
    #pragma unroll
    for (int kit = 0; kit < 4; kit++)
        af[kit] = *(const bf16x8*)(A + (size_t)(m0 + lrow) * CDIM + kit * 32 + quad * 8);

    // hoist wkp1 for this lane's 4 output rows (quad*4 + r)
    float wy[4], wx[4];
    #pragma unroll
    for (int r = 0; r < 4; r++) {
        int gr = m0 + quad * 4 + r;
        wy[r] = wkp1[2 * gr]; wx[r] = wkp1[2 * gr + 1];
    }

    const float thr = 2.0f * sqrtf(32.0f) + 0.1f;
    const float thr2 = thr * thr;

    // ---- sweep 128 col-tiles of 16
    for (int ct = 0; ct < 128; ct++) {
        const int col = colbase + ct * 16 + lrow;     // true column (B-frag + mask)
        f32x4 acc = (f32x4){0.f, 0.f, 0.f, 0.f};
        #pragma unroll
        for (int kit = 0; kit < 4; kit++) {
            bf16x8 bf = *(const bf16x8*)(B + (size_t)col * CDIM + kit * 32 + quad * 8);
            acc = __builtin_amdgcn_mfma_f32_16x16x32_bf16(af[kit], bf, acc, 0, 0, 0);
        }
        const float ky = kp2[2 * col], kx = kp2[2 * col + 1];
        #pragma unroll
        for (int r = 0; r < 4; r++) {
            const int row = quad * 4 + r;             // local row; C: row=quad*4+reg
            float dy = wy[r] - ky, dx = wx[r] - kx;
            float v = acc[r];
            if (dy * dy + dx * dx <= thr2) v -= 5.0f;
            unsigned key = bits2key((unsigned)f2bf(v));
            bool cd = key > T0KEY;
            unsigned long long m = __ballot(cd);
            unsigned sub = (unsigned)(m >> (quad * 16)) & 0xFFFFu;
            int base = 0;
            if (lrow == 0 && sub)
                base = (int)atomicAdd(&cnt[row], (unsigned)__popc(sub));
            base = __shfl(base, quad * 16);           // quad-leader broadcast
            if (cd) {
                int slot = base + (int)__popc(sub & ((1u << lrow) - 1u));
                if (slot < RCAP) lists[row][slot] = (ushort)key;
            }
        }
    }
    __syncthreads();

    // ---- selection: wave w owns rows w*4..w*4+3
    for (int rr = 0; rr < 4; rr++) {
        const int row = wave * 4 + rr;
        const int n = (int)cnt[row];
        unsigned kt = 0;
        float s = 0.f; int cgt = 0;
        bool good = false;
        if (n >= 256 && n <= RCAP) {
            int chi = 0;
            for (int p = lane; p < n; p += 64)
                chi += (int)((unsigned)lists[row][p] > THIKEY);
            #pragma unroll
            for (int off = 32; off >= 1; off >>= 1) chi += __shfl_down(chi, off);
            chi = __shfl(chi, 0);
            if (chi <= 255) {
                good = true;
                int lo = (int)T0KEY, hi = (int)THIKEY;   // cnt(>lo)=n>=256, cnt(>hi)<=255
                while (hi - lo > 1) {                    // 8 iterations
                    unsigned mid = (unsigned)((lo + hi) >> 1);
                    int c = 0;
                    for (int p = lane; p < n; p += 64)
                        c += (int)((unsigned)lists[row][p] > mid);
                    #pragma unroll
                    for (int off = 32; off >= 1; off >>= 1) c += __shfl_down(c, off);
                    c = __shfl(c, 0);
                    if (c >= 256) lo = (int)mid; else hi = (int)mid;
                }
                kt = (unsigned)hi;                       // 256th-largest key (attained)
                for (int p = lane; p < n; p += 64) {
                    unsigned k = (unsigned)lists[row][p];
                    if (k > kt) { s += bf2f(key2bits(k)) - 0.2f; cgt++; }
                }
            }
        }
        if (!good) {
            // exact fallback (never taken): recompute row dots -> global scratch
            ushort* myfb = fb + ((size_t)blockIdx.x * 4 + wave) * (size_t)N2;
            const int gr = m0 + row;
            const float gwy = wkp1[2 * gr], gwx = wkp1[2 * gr + 1];
            for (int c0 = lane; c0 < N2; c0 += 64) {
                float a2 = 0.f;
                for (int k = 0; k < CDIM; k++)
                    a2 += bf2f((unsigned)A[(size_t)gr * CDIM + k])
                        * bf2f((unsigned)B[(size_t)c0 * CDIM + k]);
                float dy = gwy - kp2[2 * c0], dx = gwx - kp2[2 * c0 + 1];
                if (dy * dy + dx * dx <= thr2) a2 -= 5.0f;
                myfb[c0] = (ushort)bits2key((unsigned)f2bf(a2));
            }
            int lo = -1, hi = 65535;
            while (hi - lo > 1) {
                unsigned mid = (unsigned)((lo + hi) >> 1);
                int c = 0;
                for (int p = lane; p < N2; p += 64)
                    c += (int)((unsigned)myfb[p] > mid);
                #pragma unroll
                for (int off = 32; off >= 1; off >>= 1) c += __shfl_down(c, off);
                c = __shfl(c, 0);
                if (c >= 256) lo = (int)mid; else hi = (int)mid;
            }
            kt = (unsigned)hi;
            s = 0.f; cgt = 0;
            for (int p = lane; p < N2; p += 64) {
                unsigned k = (unsigned)myfb[p];
                if (k > kt) { s += fmaxf(bf2f(key2bits(k)) - 0.2f, 0.f); cgt++; }
            }
        }
        #pragma unroll
        for (int off = 32; off >= 1; off >>= 1) {
            s += __shfl_down(s, off);
            cgt += __shfl_down(cgt, off);
        }
        if (lane == 0) {
            float vt = bf2f(key2bits(kt));
            float S = s + (float)(256 - cgt) * fmaxf(vt - 0.2f, 0.0f);
            rloss[m0 + row] = S * INV_DENOM;
        }
    }
}

// ---------- final reduce: sum 2*N1 floats -> out[0] ----------
__global__ void reduce_kernel(const float* __restrict__ a, float* __restrict__ out) {
    const int t = threadIdx.x;
    float s = 0.f;
    for (int i = t; i < 2 * N1; i += 256) s += a[i];
    #pragma unroll
    for (int off = 32; off >= 1; off >>= 1) s += __shfl_down(s, off);
    __shared__ float ws[4];
    int wave = t >> 6, lane = t & 63;
    if (lane == 0) ws[wave] = s;
    __syncthreads();
    if (t == 0) out[0] = ws[0] + ws[1] + ws[2] + ws[3];
}

extern "C" void kernel_launch(void* const* d_in, const int* in_sizes, int n_in,
                              void* d_out, int out_size, void* d_ws, size_t ws_size,
                              hipStream_t stream) {
    const float* wkp1  = (const float*)d_in[1];
    const float* kp2   = (const float*)d_in[2];
    const float* kp1d  = (const float*)d_in[3];
    const float* kp2d  = (const float*)d_in[4];
    const float* desc2 = (const float*)d_in[5];
    float* out = (float*)d_out;

    ushort* Abf  = (ushort*)d_ws;                          // 2 MB
    ushort* Bbf  = Abf + (size_t)N1 * CDIM;                // 2 MB
    float*  loss = (float*)(Bbf + (size_t)N2 * CDIM);      // 64 KB (pos | rows)
    float*  d2T  = loss + 2 * N1;                          // 2.4 MB
    ushort* fb   = (ushort*)(d2T + (size_t)NPIX * CDIM);   // 32 MB fallback scratch

    int n4 = N1 * CDIM / 4;
    cvt_kernel<<<(n4 + 255) / 256, 256, 0, stream>>>(kp1d, Abf, n4);
    cvt_kernel<<<(n4 + 255) / 256, 256, 0, stream>>>(kp2d, Bbf, n4);
    tr_kernel<<<(NPIX * CDIM + 255) / 256, 256, 0, stream>>>(desc2, d2T);

    pos_kernel<<<N1, 128, 0, stream>>>(wkp1, kp1d, d2T, loss);

    fused_kernel<<<N1 / ROWS_PB, 256, 0, stream>>>(Abf, Bbf, wkp1, kp2,
                                                   loss + N1, fb);

    reduce_kernel<<<1, 256, 0, stream>>>(loss, out);
}

// Round 15
// 626.506 us; speedup vs baseline: 4.6680x; 4.6680x over previous
//
#include <hip/hip_runtime.h>
#include <hip/hip_bf16.h>

#define N1 8192
#define N2 8192
#define CDIM 128
#define HC 60
#define WC 80
#define HIMG 480
#define WIMG 640
#define NPIX (HC * WC)
#define INV_DENOM (1.0f / (8192.0f * 256.0f))
// R14 post-mortem: T0 = 8.0 gave ~1950 candidates/row vs RCAP 1536 ->
// fallback fired for EVERY row (WRITE_SIZE was exactly 8192x16KB). R9's
// verified bracket is 12.0: mean ~1185, sigma ~32 -> n>=256 at -29sig,
// n<=1536 at +11sig, cnt(>32)<=255 at +47sig. All checked per row.
#define T0KEY  0xC140u      // monotone key of bf16(12.0)
#define THIKEY 0xC200u      // monotone key of bf16(32.0)
#define ROWS_PB 16          // rows per block
#define RCAP 1536           // per-row candidate cap

using bf16x8 = __attribute__((ext_vector_type(8))) short;
using f32x4  = __attribute__((ext_vector_type(4))) float;

__device__ __forceinline__ ushort f2bf(float f) {
    union { float f; unsigned u; } x; x.f = f;
    unsigned u = x.u;
    unsigned r = (u + 0x7FFFu + ((u >> 16) & 1u)) >> 16;
    return (ushort)r;
}
__device__ __forceinline__ float bf2f(unsigned bits) {
    union { unsigned u; float f; } x; x.u = bits << 16; return x.f;
}
__device__ __forceinline__ unsigned bits2key(unsigned b) {
    return b ^ ((b & 0x8000u) ? 0xFFFFu : 0x8000u);
}
__device__ __forceinline__ unsigned key2bits(unsigned k) {
    return k ^ ((k & 0x8000u) ? 0x8000u : 0xFFFFu);
}

// ---------- fp32 -> bf16 convert ----------
__global__ void cvt_kernel(const float* __restrict__ in, ushort* __restrict__ out, int n4) {
    int i = blockIdx.x * blockDim.x + threadIdx.x;
    if (i < n4) {
        float4 v = ((const float4*)in)[i];
        ushort4 o;
        o.x = f2bf(v.x); o.y = f2bf(v.y); o.z = f2bf(v.z); o.w = f2bf(v.w);
        ((ushort4*)out)[i] = o;
    }
}

// ---------- desc2 transpose, read-coalesced ----------
__global__ void tr_kernel(const float* __restrict__ in, float* __restrict__ out) {
    int e = blockIdx.x * blockDim.x + threadIdx.x;   // 614400 elements
    if (e < NPIX * CDIM) {
        int c = e / NPIX;
        int p = e - c * NPIX;
        out[(size_t)p * CDIM + c] = in[e];
    }
}

// ---------- positive term (coalesced, plain store) ----------
__global__ void pos_kernel(const float* __restrict__ wkp1,
                           const float* __restrict__ kp1d,
                           const float* __restrict__ desc2T,
                           float* __restrict__ ploss) {
    const int i = blockIdx.x;
    const int c = threadIdx.x;            // 128 threads = 2 waves
    float y = wkp1[2 * i], x = wkp1[2 * i + 1];
    float py = fminf(fmaxf(y / (float)(HIMG - 1) * (float)(HC - 1), 0.0f), (float)(HC - 1));
    float px = fminf(fmaxf(x / (float)(WIMG - 1) * (float)(WC - 1), 0.0f), (float)(WC - 1));
    int y0 = min(max((int)floorf(py), 0), HC - 2);
    int x0 = min(max((int)floorf(px), 0), WC - 2);
    float wy = py - (float)y0;
    float wx = px - (float)x0;
    const int p00 = y0 * WC + x0;
    float v00 = desc2T[(size_t)p00 * CDIM + c];
    float v01 = desc2T[(size_t)(p00 + 1) * CDIM + c];
    float v10 = desc2T[(size_t)(p00 + WC) * CDIM + c];
    float v11 = desc2T[(size_t)(p00 + WC + 1) * CDIM + c];
    float v = v00 * (1.0f - wy) * (1.0f - wx) + v01 * (1.0f - wy) * wx
            + v10 * wy * (1.0f - wx) + v11 * wy * wx;
    float a = kp1d[(size_t)i * CDIM + c];
    float s2 = v * v, sav = a * v;
    #pragma unroll
    for (int off = 32; off >= 1; off >>= 1) {
        s2  += __shfl_down(s2, off);
        sav += __shfl_down(sav, off);
    }
    __shared__ float p2[2], pav[2];
    int wave = threadIdx.x >> 6, lane = threadIdx.x & 63;
    if (lane == 0) { p2[wave] = s2; pav[wave] = sav; }
    __syncthreads();
    if (threadIdx.x == 0) {
        float nrm = sqrtf(p2[0] + p2[1]);
        float pd = (pav[0] + pav[1]) / fmaxf(nrm, 1e-12f);
        float l = fmaxf(1.0f - pd, 0.0f) * (256.0f / 3.0f);
        ploss[i] = l * INV_DENOM;
    }
}

// ---------- FUSED masked-GEMM + top-256 hinge select ----------
// dots NEVER touch HBM. Block = 16 rows x all 8192 cols; wave = 2048-col
// strip. A-frags hoisted to VGPRs; B global reads are L2-resident (2 MB
// fits per-XCD L2). Candidates (key > 12.0) -> per-row LDS lists via quad
// ballot + LDS atomic (distinct addrs, CU-local). One barrier, then each
// wave bisects 4 rows' ~1185-entry lists (checked brackets; exact
// recompute-fallback to global scratch, cold by >10-sigma margins).
__global__ __launch_bounds__(256)
void fused_kernel(const ushort* __restrict__ A, const ushort* __restrict__ B,
                  const float* __restrict__ wkp1, const float* __restrict__ kp2,
                  float* __restrict__ rloss, ushort* __restrict__ fb) {
    const int m0 = blockIdx.x * ROWS_PB;          // 512 blocks
    const int wave = threadIdx.x >> 6;
    const int lane = threadIdx.x & 63;
    const int lrow = lane & 15, quad = lane >> 4;
    const int colbase = wave * (N2 / 4);

    __shared__ ushort lists[ROWS_PB][RCAP];       // 48 KB
    __shared__ unsigned cnt[ROWS_PB];

    if (threadIdx.x < ROWS_PB) cnt[threadIdx.x] = 0u;
    __syncthreads();

    // hoist A-frags (rows m0..m0+15, lane row = lrow): 4 k-steps
    bf16x8 af[4];
    #pragma unroll
    for (int kit = 0; kit < 4; kit++)
        af[kit] = *(const bf16x8*)(A + (size_t)(m0 + lrow) * CDIM + kit * 32 + quad * 8);

    // hoist wkp1 for this lane's 4 output rows (quad*4 + r)
    float wy[4], wx[4];
    #pragma unroll
    for (int r = 0; r < 4; r++) {
        int gr = m0 + quad * 4 + r;
        wy[r] = wkp1[2 * gr]; wx[r] = wkp1[2 * gr + 1];
    }

    const float thr = 2.0f * sqrtf(32.0f) + 0.1f;
    const float thr2 = thr * thr;

    // ---- sweep 128 col-tiles of 16
    for (int ct = 0; ct < 128; ct++) {
        const int col = colbase + ct * 16 + lrow;     // true column (B-frag + mask)
        f32x4 acc = (f32x4){0.f, 0.f, 0.f, 0.f};
        #pragma unroll
        for (int kit = 0; kit < 4; kit++) {
            bf16x8 bf = *(const bf16x8*)(B + (size_t)col * CDIM + kit * 32 + quad * 8);
            acc = __builtin_amdgcn_mfma_f32_16x16x32_bf16(af[kit], bf, acc, 0, 0, 0);
        }
        const float ky = kp2[2 * col], kx = kp2[2 * col + 1];
        #pragma unroll
        for (int r = 0; r < 4; r++) {
            const int row = quad * 4 + r;             // local row; C: row=quad*4+reg
            float dy = wy[r] - ky, dx = wx[r] - kx;
            float v = acc[r];
            if (dy * dy + dx * dx <= thr2) v -= 5.0f;
            unsigned key = bits2key((unsigned)f2bf(v));
            bool cd = key > T0KEY;
            unsigned long long m = __ballot(cd);
            unsigned sub = (unsigned)(m >> (quad * 16)) & 0xFFFFu;
            int base = 0;
            if (lrow == 0 && sub)
                base = (int)atomicAdd(&cnt[row], (unsigned)__popc(sub));
            base = __shfl(base, quad * 16);           // quad-leader broadcast
            if (cd) {
                int slot = base + (int)__popc(sub & ((1u << lrow) - 1u));
                if (slot < RCAP) lists[row][slot] = (ushort)key;
            }
        }
    }
    __syncthreads();

    // ---- selection: wave w owns rows w*4..w*4+3
    for (int rr = 0; rr < 4; rr++) {
        const int row = wave * 4 + rr;
        const int n = (int)cnt[row];
        unsigned kt = 0;
        float s = 0.f; int cgt = 0;
        bool good = false;
        if (n >= 256 && n <= RCAP) {
            int chi = 0;
            for (int p = lane; p < n; p += 64)
                chi += (int)((unsigned)lists[row][p] > THIKEY);
            #pragma unroll
            for (int off = 32; off >= 1; off >>= 1) chi += __shfl_down(chi, off);
            chi = __shfl(chi, 0);
            if (chi <= 255) {
                good = true;
                int lo = (int)T0KEY, hi = (int)THIKEY;   // cnt(>lo)=n>=256, cnt(>hi)<=255
                while (hi - lo > 1) {                    // ~8 iterations
                    unsigned mid = (unsigned)((lo + hi) >> 1);
                    int c = 0;
                    for (int p = lane; p < n; p += 64)
                        c += (int)((unsigned)lists[row][p] > mid);
                    #pragma unroll
                    for (int off = 32; off >= 1; off >>= 1) c += __shfl_down(c, off);
                    c = __shfl(c, 0);
                    if (c >= 256) lo = (int)mid; else hi = (int)mid;
                }
                kt = (unsigned)hi;                       // 256th-largest key (attained)
                for (int p = lane; p < n; p += 64) {
                    unsigned k = (unsigned)lists[row][p];
                    if (k > kt) { s += bf2f(key2bits(k)) - 0.2f; cgt++; }
                }
            }
        }
        if (!good) {
            // exact fallback (cold): recompute row dots -> global scratch
            ushort* myfb = fb + ((size_t)blockIdx.x * 4 + wave) * (size_t)N2;
            const int gr = m0 + row;
            const float gwy = wkp1[2 * gr], gwx = wkp1[2 * gr + 1];
            for (int c0 = lane; c0 < N2; c0 += 64) {
                float a2 = 0.f;
                for (int k = 0; k < CDIM; k++)
                    a2 += bf2f((unsigned)A[(size_t)gr * CDIM + k])
                        * bf2f((unsigned)B[(size_t)c0 * CDIM + k]);
                float dy = gwy - kp2[2 * c0], dx = gwx - kp2[2 * c0 + 1];
                if (dy * dy + dx * dx <= thr2) a2 -= 5.0f;
                myfb[c0] = (ushort)bits2key((unsigned)f2bf(a2));
            }
            int lo = -1, hi = 65535;
            while (hi - lo > 1) {
                unsigned mid = (unsigned)((lo + hi) >> 1);
                int c = 0;
                for (int p = lane; p < N2; p += 64)
                    c += (int)((unsigned)myfb[p] > mid);
                #pragma unroll
                for (int off = 32; off >= 1; off >>= 1) c += __shfl_down(c, off);
                c = __shfl(c, 0);
                if (c >= 256) lo = (int)mid; else hi = (int)mid;
            }
            kt = (unsigned)hi;
            s = 0.f; cgt = 0;
            for (int p = lane; p < N2; p += 64) {
                unsigned k = (unsigned)myfb[p];
                if (k > kt) { s += fmaxf(bf2f(key2bits(k)) - 0.2f, 0.f); cgt++; }
            }
        }
        #pragma unroll
        for (int off = 32; off >= 1; off >>= 1) {
            s += __shfl_down(s, off);
            cgt += __shfl_down(cgt, off);
        }
        if (lane == 0) {
            float vt = bf2f(key2bits(kt));
            float S = s + (float)(256 - cgt) * fmaxf(vt - 0.2f, 0.0f);
            rloss[m0 + row] = S * INV_DENOM;
        }
    }
}

// ---------- final reduce: sum 2*N1 floats -> out[0] ----------
__global__ void reduce_kernel(const float* __restrict__ a, float* __restrict__ out) {
    const int t = threadIdx.x;
    float s = 0.f;
    for (int i = t; i < 2 * N1; i += 256) s += a[i];
    #pragma unroll
    for (int off = 32; off >= 1; off >>= 1) s += __shfl_down(s, off);
    __shared__ float ws[4];
    int wave = t >> 6, lane = t & 63;
    if (lane == 0) ws[wave] = s;
    __syncthreads();
    if (t == 0) out[0] = ws[0] + ws[1] + ws[2] + ws[3];
}

extern "C" void kernel_launch(void* const* d_in, const int* in_sizes, int n_in,
                              void* d_out, int out_size, void* d_ws, size_t ws_size,
                              hipStream_t stream) {
    const float* wkp1  = (const float*)d_in[1];
    const float* kp2   = (const float*)d_in[2];
    const float* kp1d  = (const float*)d_in[3];
    const float* kp2d  = (const float*)d_in[4];
    const float* desc2 = (const float*)d_in[5];
    float* out = (float*)d_out;

    ushort* Abf  = (ushort*)d_ws;                          // 2 MB
    ushort* Bbf  = Abf + (size_t)N1 * CDIM;                // 2 MB
    float*  loss = (float*)(Bbf + (size_t)N2 * CDIM);      // 64 KB (pos | rows)
    float*  d2T  = loss + 2 * N1;                          // 2.4 MB
    ushort* fb   = (ushort*)(d2T + (size_t)NPIX * CDIM);   // 32 MB fallback scratch

    int n4 = N1 * CDIM / 4;
    cvt_kernel<<<(n4 + 255) / 256, 256, 0, stream>>>(kp1d, Abf, n4);
    cvt_kernel<<<(n4 + 255) / 256, 256, 0, stream>>>(kp2d, Bbf, n4);
    tr_kernel<<<(NPIX * CDIM + 255) / 256, 256, 0, stream>>>(desc2, d2T);

    pos_kernel<<<N1, 128, 0, stream>>>(wkp1, kp1d, d2T, loss);

    fused_kernel<<<N1 / ROWS_PB, 256, 0, stream>>>(Abf, Bbf, wkp1, kp2,
                                                   loss + N1, fb);

    reduce_kernel<<<1, 256, 0, stream>>>(loss, out);
}

// Round 16
// 203.234 us; speedup vs baseline: 14.3901x; 3.0827x over previous
//
#include <hip/hip_runtime.h>
#include <hip/hip_bf16.h>

#define N1 8192
#define N2 8192
#define CDIM 128
#define HC 60
#define WC 80
#define HIMG 480
#define WIMG 640
#define NPIX (HC * WC)
#define INV_DENOM (1.0f / (8192.0f * 256.0f))
#define T0KEY  0xC100u      // monotone key of bf16(8.0)
#define THIKEY 0xC200u      // monotone key of bf16(32.0)
#define SEGCAP 2048         // u32 pairs per row list (mean ~870, +40 sigma)
#define PADK 136            // LDS row stride (128 + 8 ushort): keeps 16B align

using bf16x8 = __attribute__((ext_vector_type(8))) short;
using f32x4  = __attribute__((ext_vector_type(4))) float;

__device__ __forceinline__ ushort f2bf(float f) {
    union { float f; unsigned u; } x; x.f = f;
    unsigned u = x.u;
    unsigned r = (u + 0x7FFFu + ((u >> 16) & 1u)) >> 16;
    return (ushort)r;
}
__device__ __forceinline__ float bf2f(unsigned bits) {
    union { unsigned u; float f; } x; x.u = bits << 16; return x.f;
}
__device__ __forceinline__ unsigned key2bits(unsigned k) {
    return k ^ ((k & 0x8000u) ? 0x8000u : 0xFFFFu);
}
__device__ __forceinline__ unsigned pair2key(unsigned x) {   // packed pair transform
    return x ^ 0x80008000u ^ (((x >> 15) & 0x00010001u) * 0x7FFFu);
}

// ---------- fp32 -> bf16 convert ----------
__global__ void cvt_kernel(const float* __restrict__ in, ushort* __restrict__ out, int n4) {
    int i = blockIdx.x * blockDim.x + threadIdx.x;
    if (i < n4) {
        float4 v = ((const float4*)in)[i];
        ushort4 o;
        o.x = f2bf(v.x); o.y = f2bf(v.y); o.z = f2bf(v.z); o.w = f2bf(v.w);
        ((ushort4*)out)[i] = o;
    }
}

// ---------- desc2 transpose, read-coalesced ----------
__global__ void tr_kernel(const float* __restrict__ in, float* __restrict__ out) {
    int e = blockIdx.x * blockDim.x + threadIdx.x;   // 614400 elements
    if (e < NPIX * CDIM) {
        int c = e / NPIX;
        int p = e - c * NPIX;
        out[(size_t)p * CDIM + c] = in[e];
    }
}

// ---------- positive term (coalesced, plain store) ----------
__global__ void pos_kernel(const float* __restrict__ wkp1,
                           const float* __restrict__ kp1d,
                           const float* __restrict__ desc2T,
                           float* __restrict__ ploss) {
    const int i = blockIdx.x;
    const int c = threadIdx.x;            // 128 threads = 2 waves
    float y = wkp1[2 * i], x = wkp1[2 * i + 1];
    float py = fminf(fmaxf(y / (float)(HIMG - 1) * (float)(HC - 1), 0.0f), (float)(HC - 1));
    float px = fminf(fmaxf(x / (float)(WIMG - 1) * (float)(WC - 1), 0.0f), (float)(WC - 1));
    int y0 = min(max((int)floorf(py), 0), HC - 2);
    int x0 = min(max((int)floorf(px), 0), WC - 2);
    float wy = py - (float)y0;
    float wx = px - (float)x0;
    const int p00 = y0 * WC + x0;
    float v00 = desc2T[(size_t)p00 * CDIM + c];
    float v01 = desc2T[(size_t)(p00 + 1) * CDIM + c];
    float v10 = desc2T[(size_t)(p00 + WC) * CDIM + c];
    float v11 = desc2T[(size_t)(p00 + WC + 1) * CDIM + c];
    float v = v00 * (1.0f - wy) * (1.0f - wx) + v01 * (1.0f - wy) * wx
            + v10 * wy * (1.0f - wx) + v11 * wy * wx;
    float a = kp1d[(size_t)i * CDIM + c];
    float s2 = v * v, sav = a * v;
    #pragma unroll
    for (int off = 32; off >= 1; off >>= 1) {
        s2  += __shfl_down(s2, off);
        sav += __shfl_down(sav, off);
    }
    __shared__ float p2[2], pav[2];
    int wave = threadIdx.x >> 6, lane = threadIdx.x & 63;
    if (lane == 0) { p2[wave] = s2; pav[wave] = sav; }
    __syncthreads();
    if (threadIdx.x == 0) {
        float nrm = sqrtf(p2[0] + p2[1]);
        float pd = (pav[0] + pav[1]) / fmaxf(nrm, 1e-12f);
        float l = fmaxf(1.0f - pd, 0.0f) * (256.0f / 3.0f);
        ploss[i] = l * INV_DENOM;
    }
}

// ---------- masked GEMM, LDS-staged (m93-style), packed permuted stores ----------
// R15 post-mortem: fused design dead; R12 gemm (direct global fragment loads,
// no staging) ran at 198 TF = step-0 of the measured ladder. CDIM=128 fits
// entirely in LDS: stage A-tile + B-tile (32 KB each + pad) ONCE with fully
// coalesced uint4 copies, then all 64 MFMAs read ds_read_b128 fragments.
// Row pad +8 ushort (16B-aligned) spreads banks. 70 KB LDS -> 2 blocks/CU.
__global__ __launch_bounds__(256, 2)
void gemm_kernel(const ushort* __restrict__ A, const ushort* __restrict__ B,
                 const float* __restrict__ wkp1, const float* __restrict__ kp2,
                 ushort* __restrict__ dots, int m_off) {
    __shared__ ushort sA[128 * PADK];     // 34 KB
    __shared__ ushort sB[128 * PADK];     // 34 KB
    __shared__ float s_w[256], s_k[256];  // 2 KB coords

    const int t = threadIdx.x;
    const int n0 = blockIdx.x * 128;
    const int m0 = m_off + blockIdx.y * 128;

    s_w[t] = wkp1[2 * m0 + t];
    s_k[t] = kp2[2 * n0 + t];

    // stage both tiles: contiguous 32 KB bands, 8 uint4 per thread each
    {
        const uint4* Ag = (const uint4*)(A + (size_t)m0 * CDIM);
        const uint4* Bg = (const uint4*)(B + (size_t)n0 * CDIM);
        #pragma unroll
        for (int r = 0; r < 8; r++) {
            int g = t + 256 * r;          // uint4 index 0..2047
            int row = g >> 4;             // 16 uint4 per 128-elem row
            int k8 = g & 15;
            uint4 va = Ag[g];
            uint4 vb = Bg[g];
            *(uint4*)(sA + row * PADK + k8 * 8) = va;
            *(uint4*)(sB + row * PADK + k8 * 8) = vb;
        }
    }
    __syncthreads();

    const int lane = t & 63;
    const int wave = t >> 6;
    const int wm = wave >> 1, wn = wave & 1;
    const int lrow = lane & 15, quad = lane >> 4;

    f32x4 acc[4][4];
    #pragma unroll
    for (int i = 0; i < 4; i++)
        #pragma unroll
        for (int j = 0; j < 4; j++) acc[i][j] = (f32x4){0.f, 0.f, 0.f, 0.f};

    #pragma unroll
    for (int kit = 0; kit < 4; kit++) {
        const int kk = kit * 32 + quad * 8;
        bf16x8 af[4], bfr[4];
        #pragma unroll
        for (int mt = 0; mt < 4; mt++)
            af[mt] = *(const bf16x8*)(sA + (wm * 64 + mt * 16 + lrow) * PADK + kk);
        #pragma unroll
        for (int nt = 0; nt < 4; nt++)
            bfr[nt] = *(const bf16x8*)(sB + (wn * 64 + nt * 16 + lrow) * PADK + kk);
        #pragma unroll
        for (int mt = 0; mt < 4; mt++)
            #pragma unroll
            for (int nt = 0; nt < 4; nt++)
                acc[mt][nt] = __builtin_amdgcn_mfma_f32_16x16x32_bf16(
                    af[mt], bfr[nt], acc[mt][nt], 0, 0, 0);
    }

    // epilogue (proven in R11/R12): mask with TRUE cols, pack 4 same-row
    // values, one 8B store per (mt,r); quad writes one full 128B line.
    float ky[4], kx[4];
    #pragma unroll
    for (int nt = 0; nt < 4; nt++) {
        int jl = wn * 64 + nt * 16 + lrow;
        ky[nt] = s_k[2 * jl]; kx[nt] = s_k[2 * jl + 1];
    }
    const float thr = 2.0f * sqrtf(32.0f) + 0.1f;
    const float thr2 = thr * thr;
    const size_t colbase = (size_t)(n0 + wn * 64 + lrow * 4);
    #pragma unroll
    for (int mt = 0; mt < 4; mt++) {
        #pragma unroll
        for (int r = 0; r < 4; r++) {
            const int il = wm * 64 + mt * 16 + quad * 4 + r;      // local row
            const int i = m0 + il;
            const float wy = s_w[2 * il], wx = s_w[2 * il + 1];
            unsigned h[4];
            #pragma unroll
            for (int nt = 0; nt < 4; nt++) {
                float dy = wy - ky[nt], dx = wx - kx[nt];
                float v = acc[mt][nt][r];
                if (dy * dy + dx * dx <= thr2) v -= 5.0f;
                h[nt] = (unsigned)f2bf(v);
            }
            unsigned long long pk = (unsigned long long)(h[0] | (h[1] << 16))
                                  | ((unsigned long long)(h[2] | (h[3] << 16)) << 32);
            *(unsigned long long*)(dots + (size_t)(i - m_off) * N2 + colbase) = pk;
        }
    }
}

// ---------- per-row top-256 hinge sum: WAVE per row, scan compaction ----------
// (unchanged from R13: passed, ~20 us/chunk by subtraction)
__global__ __launch_bounds__(256)
void select_kernel(const ushort* __restrict__ dots, float* __restrict__ rloss,
                   int m_off) {
    const int wave = threadIdx.x >> 6;
    const int lane = threadIdx.x & 63;
    const int row = blockIdx.x * 4 + wave;

    __shared__ unsigned seg[4][SEGCAP];    // 32 KB
    unsigned* lst = seg[wave];

    const uint4* rp4 = (const uint4*)(dots + (size_t)row * N2);  // 1024 uint4
    const unsigned T0HI  = (T0KEY << 16) | 0xFFFFu;
    const unsigned THIHI = (THIKEY << 16) | 0xFFFFu;

    // ---- pass A: per-lane counts (no cross-lane ops)
    int myc = 0, clh = 0, chh = 0;
    #pragma unroll
    for (int j = 0; j < 16; j++) {
        uint4 w = rp4[lane + 64 * j];
        unsigned xs[4] = {w.x, w.y, w.z, w.w};
        #pragma unroll
        for (int u = 0; u < 4; u++) {
            unsigned kk = pair2key(xs[u]);
            unsigned lowk = kk & 0xFFFFu;
            int ql = (int)(lowk > T0KEY), qh = (int)(kk > T0HI);
            clh += ql + qh;
            chh += (int)(lowk > THIKEY) + (int)(kk > THIHI);
            myc += (ql | qh);
        }
    }
    int inc = myc, rl = clh, rh = chh;
    #pragma unroll
    for (int off = 1; off < 64; off <<= 1) {
        int tt = __shfl_up(inc, off);
        if (lane >= off) inc += tt;
        rl += __shfl_down(rl, off);
        rh += __shfl_down(rh, off);
    }
    const int mybase = inc - myc;
    const int len = __shfl(inc, 63);
    const int totLow = __shfl(rl, 0);
    const int totHi  = __shfl(rh, 0);
    const bool ok = (totLow >= 256) && (totHi <= 255) && (len <= SEGCAP);

    unsigned kt;
    float s = 0.f; int cgt = 0;

    if (ok) {
        int ofs = mybase;
        #pragma unroll
        for (int j = 0; j < 16; j++) {
            uint4 w = rp4[lane + 64 * j];
            unsigned xs[4] = {w.x, w.y, w.z, w.w};
            #pragma unroll
            for (int u = 0; u < 4; u++) {
                unsigned kk = pair2key(xs[u]);
                if ((kk & 0xFFFFu) > T0KEY || kk > T0HI) lst[ofs++] = kk;
            }
        }
        int lo = (int)T0KEY, hi = (int)THIKEY;
        while (hi - lo > 1) {
            unsigned midu = (unsigned)((lo + hi) >> 1);
            unsigned midhi = (midu << 16) | 0xFFFFu;
            int c = 0;
            for (int p = lane; p < len; p += 64) {
                unsigned x = lst[p];
                c += (int)((x & 0xFFFFu) > midu) + (int)(x > midhi);
            }
            #pragma unroll
            for (int off = 32; off >= 1; off >>= 1) c += __shfl_down(c, off);
            c = __shfl(c, 0);
            if (c >= 256) lo = (int)midu; else hi = (int)midu;
        }
        kt = (unsigned)hi;
        const unsigned kthi = (kt << 16) | 0xFFFFu;
        for (int p = lane; p < len; p += 64) {
            unsigned x = lst[p];
            unsigned lowk = x & 0xFFFFu, highk = x >> 16;
            if (lowk > kt) { s += bf2f(key2bits(lowk))  - 0.2f; cgt++; }
            if (x > kthi)  { s += bf2f(key2bits(highk)) - 0.2f; cgt++; }
        }
    } else {
        int lo = -1, hi = 65535;
        while (hi - lo > 1) {
            unsigned midu = (unsigned)((lo + hi) >> 1);
            unsigned midhi = (midu << 16) | 0xFFFFu;
            int c = 0;
            for (int j = 0; j < 16; j++) {
                uint4 w = rp4[lane + 64 * j];
                unsigned xs[4] = {w.x, w.y, w.z, w.w};
                #pragma unroll
                for (int u = 0; u < 4; u++) {
                    unsigned kk = pair2key(xs[u]);
                    c += (int)((kk & 0xFFFFu) > midu) + (int)(kk > midhi);
                }
            }
            #pragma unroll
            for (int off = 32; off >= 1; off >>= 1) c += __shfl_down(c, off);
            c = __shfl(c, 0);
            if (c >= 256) lo = (int)midu; else hi = (int)midu;
        }
        kt = (unsigned)hi;
        const unsigned kthi = (kt << 16) | 0xFFFFu;
        for (int j = 0; j < 16; j++) {
            uint4 w = rp4[lane + 64 * j];
            unsigned xs[4] = {w.x, w.y, w.z, w.w};
            #pragma unroll
            for (int u = 0; u < 4; u++) {
                unsigned kk = pair2key(xs[u]);
                unsigned lowk = kk & 0xFFFFu, highk = kk >> 16;
                if (lowk > kt) { s += fmaxf(bf2f(key2bits(lowk))  - 0.2f, 0.f); cgt++; }
                if (kk > kthi) { s += fmaxf(bf2f(key2bits(highk)) - 0.2f, 0.f); cgt++; }
            }
        }
    }

    #pragma unroll
    for (int off = 32; off >= 1; off >>= 1) {
        s += __shfl_down(s, off);
        cgt += __shfl_down(cgt, off);
    }
    if (lane == 0) {
        float vt = bf2f(key2bits(kt));
        float S = s + (float)(256 - cgt) * fmaxf(vt - 0.2f, 0.0f);
        rloss[m_off + row] = S * INV_DENOM;
    }
}

// ---------- final reduce: sum 2*N1 floats -> out[0] ----------
__global__ void reduce_kernel(const float* __restrict__ a, float* __restrict__ out) {
    const int t = threadIdx.x;
    float s = 0.f;
    for (int i = t; i < 2 * N1; i += 256) s += a[i];
    #pragma unroll
    for (int off = 32; off >= 1; off >>= 1) s += __shfl_down(s, off);
    __shared__ float ws[4];
    int wave = t >> 6, lane = t & 63;
    if (lane == 0) ws[wave] = s;
    __syncthreads();
    if (t == 0) out[0] = ws[0] + ws[1] + ws[2] + ws[3];
}

extern "C" void kernel_launch(void* const* d_in, const int* in_sizes, int n_in,
                              void* d_out, int out_size, void* d_ws, size_t ws_size,
                              hipStream_t stream) {
    const float* wkp1  = (const float*)d_in[1];
    const float* kp2   = (const float*)d_in[2];
    const float* kp1d  = (const float*)d_in[3];
    const float* kp2d  = (const float*)d_in[4];
    const float* desc2 = (const float*)d_in[5];
    float* out = (float*)d_out;

    ushort* Abf   = (ushort*)d_ws;                         // 2 MB
    ushort* Bbf   = Abf + (size_t)N1 * CDIM;               // 2 MB
    float*  loss  = (float*)(Bbf + (size_t)N2 * CDIM);     // 64 KB (pos | rows)
    float*  d2T   = loss + 2 * N1;                         // 2.4 MB
    ushort* dots  = (ushort*)(d2T + (size_t)NPIX * CDIM);  // chunked dots

    size_t head_bytes = (size_t)(N1 + N2) * CDIM * sizeof(ushort)
                      + 2 * N1 * sizeof(float)
                      + (size_t)NPIX * CDIM * sizeof(float);
    size_t avail = (ws_size > head_bytes) ? (ws_size - head_bytes) : 0;
    long rows_chunk = (long)(avail / ((size_t)N2 * sizeof(ushort)));
    rows_chunk = (rows_chunk / 128) * 128;
    if (rows_chunk > N1) rows_chunk = N1;
    if (rows_chunk < 128) rows_chunk = 128;      // requires ws >= ~9 MB

    int n4 = N1 * CDIM / 4;
    cvt_kernel<<<(n4 + 255) / 256, 256, 0, stream>>>(kp1d, Abf, n4);
    cvt_kernel<<<(n4 + 255) / 256, 256, 0, stream>>>(kp2d, Bbf, n4);
    tr_kernel<<<(NPIX * CDIM + 255) / 256, 256, 0, stream>>>(desc2, d2T);

    pos_kernel<<<N1, 128, 0, stream>>>(wkp1, kp1d, d2T, loss);

    for (int r0 = 0; r0 < N1; r0 += (int)rows_chunk) {
        int rows = (int)((N1 - r0 < rows_chunk) ? (N1 - r0) : rows_chunk);
        dim3 grid(N2 / 128, rows / 128);
        gemm_kernel<<<grid, 256, 0, stream>>>(Abf, Bbf, wkp1, kp2, dots, r0);
        select_kernel<<<rows / 4, 256, 0, stream>>>(dots, loss + N1, r0);
    }

    reduce_kernel<<<1, 256, 0, stream>>>(loss, out);
}